// Round 2
// baseline (1930.068 us; speedup 1.0000x reference)
//
#include <hip/hip_runtime.h>
#include <hip/hip_bf16.h>
#include <math.h>

// ---------------------------------------------------------------------------
// GCN pipeline (CSR-gather formulation, no float scatter atomics):
//  h1 = relu(gcn(x, W1, b1));  h2 = relu(gcn(h1, W2, b2));
//  g = mean-pool(h2, batch);   out = log_softmax(g @ Wfc + bfc)
//
// gcn(x)[i] = dinv[i] * ( sum_{e: col=i} x[row_e]*dinv[row_e] + x[i]*dinv[i] ) @ W + b
// Aggregation is done pre-transform (linearity): scatter/gather in input space
// (3 dims for layer 1, 16 for layer 2), W applied per-node after aggregation.
// CSR-by-destination built on the fly: deg histogram -> scan -> bucket fill.
// ---------------------------------------------------------------------------

#define TPB 256
#define SCAN_T 1024

__device__ __forceinline__ void atomAddF(float* p, float v) {
    unsafeAtomicAdd(p, v);   // hardware global_atomic_add_f32 on gfx950
}

// --- K1: in-degree count (self-loop handled as +1 later) ---
__global__ void k_deg(const int* __restrict__ col, int E, int* __restrict__ cnt) {
    int e = blockIdx.x * blockDim.x + threadIdx.x;
    if (e < E) atomicAdd(&cnt[col[e]], 1);
}

// --- K2: single-block hierarchical exclusive scan of cnt[N] -> off[], cur[] ---
__global__ void k_scan(const int* __restrict__ cnt, int* __restrict__ off,
                       int* __restrict__ cur, int N) {
    __shared__ int sh[SCAN_T];
    const int t = threadIdx.x;
    const int chunk = (N + SCAN_T - 1) / SCAN_T;
    const int lo = t * chunk;
    const int hi = min(lo + chunk, N);
    int s = 0;
    for (int i = lo; i < hi; ++i) s += cnt[i];
    sh[t] = s;
    __syncthreads();
    // Hillis-Steele inclusive scan over 1024 partials
    for (int d = 1; d < SCAN_T; d <<= 1) {
        int v = (t >= d) ? sh[t - d] : 0;
        __syncthreads();
        sh[t] += v;
        __syncthreads();
    }
    int run = (t == 0) ? 0 : sh[t - 1];
    for (int i = lo; i < hi; ++i) {
        off[i] = run;
        cur[i] = run;
        run += cnt[i];
    }
}

// --- K3: fill CSR buckets: csr[off[col].. ] = row ---
__global__ void k_build(const int* __restrict__ row, const int* __restrict__ col,
                        int* __restrict__ cur, int* __restrict__ csr, int E) {
    int e = blockIdx.x * blockDim.x + threadIdx.x;
    if (e < E) {
        int pos = atomicAdd(&cur[col[e]], 1);
        csr[pos] = row[e];
    }
}

// --- K4: dinv = rsqrt(1+cnt); y1 = x*dinv (3 dims, padded float4) ---
__global__ void k_prep1(const float* __restrict__ x, const int* __restrict__ cnt,
                        float* __restrict__ dinv, float4* __restrict__ y1, int N) {
    int i = blockIdx.x * blockDim.x + threadIdx.x;
    if (i < N) {
        float d = rsqrtf(1.0f + (float)cnt[i]);
        dinv[i] = d;
        float4 v;
        v.x = x[3*i + 0] * d;
        v.y = x[3*i + 1] * d;
        v.z = x[3*i + 2] * d;
        v.w = 0.0f;
        y1[i] = v;
    }
}

// --- K5: layer 1 = gather + scale + (3x16 GEMM) + relu + pre-scale -> y2 ---
__global__ void k_layer1(const float4* __restrict__ y1, const float* __restrict__ dinv,
                         const int* __restrict__ cnt, const int* __restrict__ off,
                         const int* __restrict__ csr,
                         const float* __restrict__ W1, const float* __restrict__ b1,
                         float* __restrict__ y2, int N) {
    __shared__ float sW[48];
    __shared__ float sb[16];
    if (threadIdx.x < 48) sW[threadIdx.x] = W1[threadIdx.x];
    if (threadIdx.x < 16) sb[threadIdx.x] = b1[threadIdx.x];
    __syncthreads();
    int i = blockIdx.x * blockDim.x + threadIdx.x;
    if (i < N) {
        float4 a = y1[i];                 // self-loop term (already scaled)
        float ax = a.x, ay = a.y, az = a.z;
        const int s = off[i];
        const int e = s + cnt[i];
#pragma unroll 4
        for (int k = s; k < e; ++k) {
            float4 v = y1[csr[k]];
            ax += v.x; ay += v.y; az += v.z;
        }
        const float d = dinv[i];
        ax *= d; ay *= d; az *= d;
        float h[16];
#pragma unroll
        for (int f = 0; f < 16; ++f) {
            float t = sb[f] + ax * sW[f] + ay * sW[16 + f] + az * sW[32 + f];
            h[f] = fmaxf(t, 0.0f) * d;    // relu then pre-scale for next layer
        }
        float4* py = (float4*)(y2 + (size_t)i * 16);
#pragma unroll
        for (int q = 0; q < 4; ++q)
            py[q] = make_float4(h[4*q], h[4*q+1], h[4*q+2], h[4*q+3]);
    }
}

// --- K6: layer 2 = gather(16f) + scale + (16x32 GEMM) + relu + mean-pool acc ---
__global__ void k_layer2(const float* __restrict__ y2, const float* __restrict__ dinv,
                         const int* __restrict__ cnt, const int* __restrict__ off,
                         const int* __restrict__ csr,
                         const float* __restrict__ W2, const float* __restrict__ b2,
                         const int* __restrict__ batch,
                         float* __restrict__ gsum, float* __restrict__ gcnt, int N) {
    __shared__ float sW[512];
    __shared__ float sb[32];
    for (int j = threadIdx.x; j < 512; j += blockDim.x) sW[j] = W2[j];
    if (threadIdx.x < 32) sb[threadIdx.x] = b2[threadIdx.x];
    __syncthreads();
    int i = blockIdx.x * blockDim.x + threadIdx.x;
    if (i < N) {
        const float4* self = (const float4*)(y2 + (size_t)i * 16);
        float4 a0 = self[0], a1 = self[1], a2 = self[2], a3 = self[3];
        const int s = off[i];
        const int e = s + cnt[i];
#pragma unroll 2
        for (int k = s; k < e; ++k) {
            const float4* p = (const float4*)(y2 + (size_t)csr[k] * 16);
            float4 v0 = p[0], v1 = p[1], v2 = p[2], v3 = p[3];
            a0.x += v0.x; a0.y += v0.y; a0.z += v0.z; a0.w += v0.w;
            a1.x += v1.x; a1.y += v1.y; a1.z += v1.z; a1.w += v1.w;
            a2.x += v2.x; a2.y += v2.y; a2.z += v2.z; a2.w += v2.w;
            a3.x += v3.x; a3.y += v3.y; a3.z += v3.z; a3.w += v3.w;
        }
        const float d = dinv[i];
        float v[16];
        v[0]=a0.x*d; v[1]=a0.y*d; v[2]=a0.z*d; v[3]=a0.w*d;
        v[4]=a1.x*d; v[5]=a1.y*d; v[6]=a1.z*d; v[7]=a1.w*d;
        v[8]=a2.x*d; v[9]=a2.y*d; v[10]=a2.z*d; v[11]=a2.w*d;
        v[12]=a3.x*d; v[13]=a3.y*d; v[14]=a3.z*d; v[15]=a3.w*d;
        const int b = batch[i];
        float* gs = gsum + (size_t)b * 32;
#pragma unroll
        for (int f = 0; f < 32; ++f) {
            float t = sb[f];
#pragma unroll
            for (int c = 0; c < 16; ++c) t += v[c] * sW[c * 32 + f];
            atomAddF(&gs[f], fmaxf(t, 0.0f));
        }
        atomAddF(&gcnt[b], 1.0f);
    }
}

// --- K7: mean -> FC -> log_softmax ---
__global__ void k_head(const float* __restrict__ gsum, const float* __restrict__ gcnt,
                       const float* __restrict__ Wfc, const float* __restrict__ bfc,
                       float* __restrict__ out, int G) {
    int g = blockIdx.x * blockDim.x + threadIdx.x;
    if (g < G) {
        float inv = 1.0f / fmaxf(gcnt[g], 1.0f);
        float l0 = bfc[0], l1 = bfc[1];
        const float* gs = gsum + (size_t)g * 32;
#pragma unroll
        for (int j = 0; j < 32; ++j) {
            float m = gs[j] * inv;
            l0 += m * Wfc[j * 2 + 0];
            l1 += m * Wfc[j * 2 + 1];
        }
        float mx = fmaxf(l0, l1);
        float lse = mx + logf(expf(l0 - mx) + expf(l1 - mx));
        out[g * 2 + 0] = l0 - lse;
        out[g * 2 + 1] = l1 - lse;
    }
}

extern "C" void kernel_launch(void* const* d_in, const int* in_sizes, int n_in,
                              void* d_out, int out_size, void* d_ws, size_t ws_size,
                              hipStream_t stream) {
    const float* x     = (const float*)d_in[0];
    const int*   edge  = (const int*)  d_in[1];
    const int*   batch = (const int*)  d_in[2];
    const float* W1    = (const float*)d_in[3];
    const float* b1    = (const float*)d_in[4];
    const float* W2    = (const float*)d_in[5];
    const float* b2    = (const float*)d_in[6];
    const float* Wfc   = (const float*)d_in[7];
    const float* bfc   = (const float*)d_in[8];

    const int N = in_sizes[0] / 3;
    const int E = in_sizes[1] / 2;
    const int G = out_size / 2;
    const int* row = edge;
    const int* col = edge + E;

    // workspace partition (256B aligned)
    char* base = (char*)d_ws;
    size_t o = 0;
    auto take = [&](size_t bytes) { char* r = base + o; o += (bytes + 255) & ~(size_t)255; return r; };
    int*    cnt  = (int*)   take((size_t)N * 4);
    int*    off  = (int*)   take((size_t)N * 4);
    int*    cur  = (int*)   take((size_t)N * 4);
    int*    csr  = (int*)   take((size_t)E * 4);
    float*  dinv = (float*) take((size_t)N * 4);
    float4* y1   = (float4*)take((size_t)N * 16);
    float*  y2   = (float*) take((size_t)N * 64);
    float*  gsum = (float*) take((size_t)G * 33 * 4);   // gsum[G*32] + gcnt[G]
    float*  gcnt = gsum + (size_t)G * 32;

    hipMemsetAsync(cnt,  0, (size_t)N * 4,      stream);
    hipMemsetAsync(gsum, 0, (size_t)G * 33 * 4, stream);

    const int gN = (N + TPB - 1) / TPB;
    const int gE = (E + TPB - 1) / TPB;
    const int gG = (G + TPB - 1) / TPB;

    k_deg   <<<gE, TPB, 0, stream>>>(col, E, cnt);
    k_scan  <<<1, SCAN_T, 0, stream>>>(cnt, off, cur, N);
    k_build <<<gE, TPB, 0, stream>>>(row, col, cur, csr, E);
    k_prep1 <<<gN, TPB, 0, stream>>>(x, cnt, dinv, y1, N);
    k_layer1<<<gN, TPB, 0, stream>>>(y1, dinv, cnt, off, csr, W1, b1, y2, N);
    k_layer2<<<gN, TPB, 0, stream>>>(y2, dinv, cnt, off, csr, W2, b2, batch, gsum, gcnt, N);
    k_head  <<<gG, TPB, 0, stream>>>(gsum, gcnt, Wfc, bfc, (float*)d_out, G);
}